// Round 1
// baseline (512.864 us; speedup 1.0000x reference)
//
#include <hip/hip_runtime.h>
#include <math.h>

#define C_DIM 256
#define N_EMB 8192
#define N_Z   8192
#define HWB   1024          // H*W per batch
#define MB    64            // z rows per block
#define NT    256           // emb cols per tile
#define KC    32            // k-chunk
#define NSPLIT 8            // codebook splits
#define LSTR  36            // LDS row stride (floats): 32 + 4 pad, 9 float4 (odd) -> conflict-free b128
#define ZQ_ELEMS (N_Z * C_DIM)

__device__ __forceinline__ float sqf(float x) { return __fmul_rn(x, x); }

// Exact replication of numpy pairwise summation of 256 squared elements:
// n=256 -> split 128+128; each 128: 8 accumulators r[j], i=8..120 step 8,
// combine ((r0+r1)+(r2+r3))+((r4+r5)+(r6+r7)); total = h0 + h1.
template <int STRIDE>
__device__ float pw_sumsq_256(const float* __restrict__ a) {
  float h[2];
#pragma unroll
  for (int hh = 0; hh < 2; ++hh) {
    const float* p = a + hh * 128 * STRIDE;
    float r0 = sqf(p[0 * STRIDE]), r1 = sqf(p[1 * STRIDE]);
    float r2 = sqf(p[2 * STRIDE]), r3 = sqf(p[3 * STRIDE]);
    float r4 = sqf(p[4 * STRIDE]), r5 = sqf(p[5 * STRIDE]);
    float r6 = sqf(p[6 * STRIDE]), r7 = sqf(p[7 * STRIDE]);
    for (int i = 8; i < 128; i += 8) {
      r0 = __fadd_rn(r0, sqf(p[(i + 0) * STRIDE]));
      r1 = __fadd_rn(r1, sqf(p[(i + 1) * STRIDE]));
      r2 = __fadd_rn(r2, sqf(p[(i + 2) * STRIDE]));
      r3 = __fadd_rn(r3, sqf(p[(i + 3) * STRIDE]));
      r4 = __fadd_rn(r4, sqf(p[(i + 4) * STRIDE]));
      r5 = __fadd_rn(r5, sqf(p[(i + 5) * STRIDE]));
      r6 = __fadd_rn(r6, sqf(p[(i + 6) * STRIDE]));
      r7 = __fadd_rn(r7, sqf(p[(i + 7) * STRIDE]));
    }
    h[hh] = __fadd_rn(__fadd_rn(__fadd_rn(r0, r1), __fadd_rn(r2, r3)),
                      __fadd_rn(__fadd_rn(r4, r5), __fadd_rn(r6, r7)));
  }
  return __fadd_rn(h[0], h[1]);
}

// blocks 0..31: e2 rows; blocks 32..63: z2 rows
__global__ void vq_norms(const float* __restrict__ hid, const float* __restrict__ emb,
                         float* __restrict__ z2, float* __restrict__ e2) {
  int t = threadIdx.x, b = blockIdx.x;
  if (b < 32) {
    int r = b * 256 + t;
    e2[r] = pw_sumsq_256<1>(emb + (size_t)r * C_DIM);
  } else {
    int n = (b - 32) * 256 + t;
    int bb = n >> 10, hw = n & 1023;
    z2[n] = pw_sumsq_256<HWB>(hid + (size_t)bb * C_DIM * HWB + hw);
  }
}

// Distance + per-split argmin. Block: 64 z-rows x (N_EMB/NSPLIT) emb cols.
// 256 threads: rg = t>>5 (8 row groups), l = t&31 (col lanes).
// Per-thread 8x8 register tile: rows rg + rr*8, cols l + jj*32 (+ tile*NT).
__global__ __launch_bounds__(256) void vq_dist(
    const float* __restrict__ hid, const float* __restrict__ emb,
    const float* __restrict__ z2g, const float* __restrict__ e2g,
    float* __restrict__ cd, int* __restrict__ ci) {
  __shared__ float zl[MB * LSTR];   //  9,216 B
  __shared__ float el[NT * LSTR];   // 36,864 B
  int t = threadIdx.x;
  int mb = blockIdx.x >> 3;        // 0..127
  int ns = blockIdx.x & (NSPLIT - 1);
  int n0z = mb * MB;
  int bb = n0z >> 10, hw0 = n0z & 1023;
  const float* hb = hid + (size_t)bb * C_DIM * HWB + hw0;

  int rg = t >> 5, l = t & 31;
  float z2r[8];
#pragma unroll
  for (int rr = 0; rr < 8; ++rr) z2r[rr] = z2g[n0z + rg + rr * 8];

  float best[8];
  int bidx[8];
#pragma unroll
  for (int rr = 0; rr < 8; ++rr) { best[rr] = INFINITY; bidx[rr] = 0; }

  const int n0e_base = ns * (N_EMB / NSPLIT);
  // staging index helpers
  const int zs_r = t & 63, zs_c0 = t >> 6;          // z: 64 rows x 4 col-groups
  const int es_k4 = t & 7, es_n = t >> 3;           // e: 8 k4 x 32 rows per pass

  for (int tile = 0; tile < (N_EMB / NSPLIT) / NT; ++tile) {
    int ne0 = n0e_base + tile * NT;
    float acc[8][8];
#pragma unroll
    for (int i = 0; i < 8; ++i)
#pragma unroll
      for (int j = 0; j < 8; ++j) acc[i][j] = 0.f;

    for (int kc = 0; kc < C_DIM / KC; ++kc) {
      __syncthreads();   // prior compute done before restaging
      // stage z chunk: zl[r][cc] = z[n0z+r][kc*32+cc]
#pragma unroll
      for (int p = 0; p < 8; ++p) {
        int cc = zs_c0 * 8 + p;
        zl[zs_r * LSTR + cc] = hb[(kc * KC + cc) * HWB + zs_r];
      }
      // stage e chunk (transpose-free, row-major [n][kk]): 8 float4/thread
#pragma unroll
      for (int p = 0; p < 8; ++p) {
        int nn = es_n + p * 32;
        float4 v = *(const float4*)(emb + (size_t)(ne0 + nn) * C_DIM + kc * KC + es_k4 * 4);
        *(float4*)(el + nn * LSTR + es_k4 * 4) = v;
      }
      __syncthreads();
#pragma unroll
      for (int k4 = 0; k4 < KC / 4; ++k4) {
        float4 zv[8], ev[8];
#pragma unroll
        for (int rr = 0; rr < 8; ++rr)
          zv[rr] = *(const float4*)(zl + (rg + rr * 8) * LSTR + k4 * 4);
#pragma unroll
        for (int jj = 0; jj < 8; ++jj)
          ev[jj] = *(const float4*)(el + (l + jj * 32) * LSTR + k4 * 4);
#pragma unroll
        for (int rr = 0; rr < 8; ++rr)
#pragma unroll
          for (int jj = 0; jj < 8; ++jj) {
            float a = acc[rr][jj];
            a = fmaf(zv[rr].x, ev[jj].x, a);
            a = fmaf(zv[rr].y, ev[jj].y, a);
            a = fmaf(zv[rr].z, ev[jj].z, a);
            a = fmaf(zv[rr].w, ev[jj].w, a);
            acc[rr][jj] = a;
          }
      }
      __syncthreads();
    }
    // scores: numpy expr fl(fl(z2+e2) - fl(2*dot)); ascending index order
#pragma unroll
    for (int jj = 0; jj < 8; ++jj) {
      int ce = ne0 + l + jj * 32;
      float e2v = e2g[ce];
#pragma unroll
      for (int rr = 0; rr < 8; ++rr) {
        float s1 = __fadd_rn(z2r[rr], e2v);
        float s = __fsub_rn(s1, __fmul_rn(2.0f, acc[rr][jj]));
        if (s < best[rr]) { best[rr] = s; bidx[rr] = ce; }
      }
    }
  }
  // reduce across the 32 lanes of each row group (xor <=16 stays in-half)
#pragma unroll
  for (int rr = 0; rr < 8; ++rr) {
    float b = best[rr];
    int i = bidx[rr];
#pragma unroll
    for (int m = 16; m >= 1; m >>= 1) {
      float ob = __shfl_xor(b, m);
      int oi = __shfl_xor(i, m);
      if (ob < b || (ob == b && oi < i)) { b = ob; i = oi; }
    }
    if (l == 0) {
      cd[ns * N_Z + n0z + rg + rr * 8] = b;
      ci[ns * N_Z + n0z + rg + rr * 8] = i;
    }
  }
}

// merge NSPLIT candidates per row, write indices (as float) and gather z_q
__global__ void vq_out(const float* __restrict__ emb, const float* __restrict__ cd,
                       const int* __restrict__ ci, float* __restrict__ out) {
  __shared__ int sidx[32];
  int t = threadIdx.x;
  int n0 = blockIdx.x * 32;
  if (t < 32) {
    int n = n0 + t;
    float b = INFINITY;
    int bi = 0;
    for (int ns = 0; ns < NSPLIT; ++ns) {        // ascending split = ascending idx
      float d = cd[ns * N_Z + n];
      int i = ci[ns * N_Z + n];
      if (d < b || (d == b && i < bi)) { b = d; bi = i; }
    }
    sidx[t] = bi;
    out[ZQ_ELEMS + n] = (float)bi;
  }
  __syncthreads();
  int bb = n0 >> 10, hw0 = n0 & 1023;
  int nl = t & 31, cg = t >> 5;   // 8 col groups of 4
#pragma unroll
  for (int p = 0; p < 8; ++p) {
    int c0 = cg * 4 + p * 32;
    float4 v = *(const float4*)(emb + (size_t)sidx[nl] * C_DIM + c0);
    out[((size_t)bb * C_DIM + c0 + 0) * HWB + hw0 + nl] = v.x;
    out[((size_t)bb * C_DIM + c0 + 1) * HWB + hw0 + nl] = v.y;
    out[((size_t)bb * C_DIM + c0 + 2) * HWB + hw0 + nl] = v.z;
    out[((size_t)bb * C_DIM + c0 + 3) * HWB + hw0 + nl] = v.w;
  }
}

extern "C" void kernel_launch(void* const* d_in, const int* in_sizes, int n_in,
                              void* d_out, int out_size, void* d_ws, size_t ws_size,
                              hipStream_t stream) {
  const float* hid = (const float*)d_in[0];
  const float* emb = (const float*)d_in[1];
  float* out = (float*)d_out;

  float* z2 = (float*)d_ws;                 // 8192
  float* e2 = z2 + N_Z;                     // 8192
  float* cd = e2 + N_EMB;                   // NSPLIT*8192
  int* ci = (int*)(cd + (size_t)NSPLIT * N_Z);  // NSPLIT*8192

  vq_norms<<<64, 256, 0, stream>>>(hid, emb, z2, e2);
  vq_dist<<<(N_Z / MB) * NSPLIT, 256, 0, stream>>>(hid, emb, z2, e2, cd, ci);
  vq_out<<<N_Z / 32, 256, 0, stream>>>(emb, cd, ci, out);
}